// Round 1
// baseline (1946.245 us; speedup 1.0000x reference)
//
#include <hip/hip_runtime.h>

#define NUM_USERS 100000
#define NUM_ITEMS 50000
#define EMBED_DIM 64
#define N_NODES   150000   // NUM_USERS + NUM_ITEMS
#define SCAN_CHUNK 2048    // 256 threads x 8 elems

// ---------------------------------------------------------------------------
// CSR build: histogram -> scan -> scatter
// ---------------------------------------------------------------------------

__global__ void k_hist(const int* __restrict__ rows, int* __restrict__ counts, int nnz) {
    int i = blockIdx.x * blockDim.x + threadIdx.x;
    if (i < nnz) atomicAdd(&counts[rows[i]], 1);
}

// Per-block exclusive scan over chunks of SCAN_CHUNK; writes per-chunk
// exclusive values into offs and chunk totals into block_sums.
__global__ void k_scan1(const int* __restrict__ counts, int* __restrict__ offs,
                        int* __restrict__ block_sums, int n) {
    __shared__ int lds[256];
    int base = blockIdx.x * SCAN_CHUNK;
    int vals[8];
    int sum = 0;
#pragma unroll
    for (int j = 0; j < 8; j++) {
        int idx = base + threadIdx.x * 8 + j;
        int v = (idx < n) ? counts[idx] : 0;
        vals[j] = sum;   // exclusive within this thread's 8
        sum += v;
    }
    lds[threadIdx.x] = sum;
    __syncthreads();
    // Hillis-Steele inclusive scan of the 256 per-thread sums
    for (int d = 1; d < 256; d <<= 1) {
        int y = (threadIdx.x >= (unsigned)d) ? lds[threadIdx.x - d] : 0;
        __syncthreads();
        lds[threadIdx.x] += y;
        __syncthreads();
    }
    int excl = lds[threadIdx.x] - sum;   // exclusive prefix of this thread
#pragma unroll
    for (int j = 0; j < 8; j++) {
        int idx = base + threadIdx.x * 8 + j;
        if (idx < n) offs[idx] = excl + vals[j];
    }
    if (threadIdx.x == 0) block_sums[blockIdx.x] = lds[255];
}

__global__ void k_scan2(const int* __restrict__ block_sums, int* __restrict__ block_base, int nb) {
    if (blockIdx.x == 0 && threadIdx.x == 0) {
        int acc = 0;
        for (int i = 0; i < nb; i++) { block_base[i] = acc; acc += block_sums[i]; }
    }
}

__global__ void k_addbase(int* __restrict__ offs, const int* __restrict__ block_base,
                          int n, int total) {
    int i = blockIdx.x * blockDim.x + threadIdx.x;
    if (i < n) offs[i] += block_base[i >> 11];   // 2048 = 1<<11
    if (i == 0) offs[n] = total;
}

__global__ void k_scatter(const int* __restrict__ rows, const int* __restrict__ cols,
                          const float* __restrict__ vals, const int* __restrict__ offs,
                          int* __restrict__ fill, int* __restrict__ csr_col,
                          float* __restrict__ csr_val, int nnz) {
    int i = blockIdx.x * blockDim.x + threadIdx.x;
    if (i < nnz) {
        int r = rows[i];
        int pos = offs[r] + atomicAdd(&fill[r], 1);
        csr_col[pos] = cols[i];
        csr_val[pos] = vals[i];
    }
}

// ---------------------------------------------------------------------------
// SpMM: one wave per row, lane = embedding dim. Gather-based, no atomics.
// Virtual-concat input: row c -> (c < split ? x_lo[c] : x_hi[c-split]).
// ---------------------------------------------------------------------------
__global__ void k_spmm(const int* __restrict__ offs, const int* __restrict__ csr_col,
                       const float* __restrict__ csr_val,
                       const float* __restrict__ x_lo, const float* __restrict__ x_hi,
                       int split, float* __restrict__ out) {
    int wave = (blockIdx.x * blockDim.x + threadIdx.x) >> 6;
    int lane = threadIdx.x & 63;
    if (wave >= N_NODES) return;
    int beg = offs[wave], end = offs[wave + 1];
    float acc = 0.f;
    for (int e = beg; e < end; e++) {
        int   c = csr_col[e];
        float v = csr_val[e];
        const float* xr = (c < split) ? (x_lo + (size_t)c * EMBED_DIM)
                                      : (x_hi + (size_t)(c - split) * EMBED_DIM);
        acc += v * xr[lane];
    }
    out[(size_t)wave * EMBED_DIM + lane] = acc;
}

// ---------------------------------------------------------------------------
// Accumulate the batch's user/item rows of the current layer into u_acc/i_acc.
// ---------------------------------------------------------------------------
__global__ void k_gather(const int* __restrict__ users, const int* __restrict__ items,
                         const float* __restrict__ x_lo, const float* __restrict__ x_hi,
                         int split, float* __restrict__ u_acc, float* __restrict__ i_acc,
                         int add, int batch) {
    int wave = (blockIdx.x * blockDim.x + threadIdx.x) >> 6;
    int lane = threadIdx.x & 63;
    if (wave >= batch) return;
    int nu = users[wave];                // node index of user
    int ni = NUM_USERS + items[wave];    // node index of item
    const float* ur = (nu < split) ? (x_lo + (size_t)nu * EMBED_DIM)
                                   : (x_hi + (size_t)(nu - split) * EMBED_DIM);
    const float* ir = (ni < split) ? (x_lo + (size_t)ni * EMBED_DIM)
                                   : (x_hi + (size_t)(ni - split) * EMBED_DIM);
    float uv = ur[lane];
    float iv = ir[lane];
    size_t o = (size_t)wave * EMBED_DIM + lane;
    if (add) { u_acc[o] += uv; i_acc[o] += iv; }
    else     { u_acc[o]  = uv; i_acc[o]  = iv; }
}

// out[b] = dot(u_acc[b], i_acc[b]) / 16   (mean = acc/4 on each side)
__global__ void k_dot(const float* __restrict__ u_acc, const float* __restrict__ i_acc,
                      float* __restrict__ out, int batch) {
    int wave = (blockIdx.x * blockDim.x + threadIdx.x) >> 6;
    int lane = threadIdx.x & 63;
    if (wave >= batch) return;
    size_t o = (size_t)wave * EMBED_DIM + lane;
    float p = u_acc[o] * i_acc[o];
#pragma unroll
    for (int d = 32; d > 0; d >>= 1) p += __shfl_down(p, d, 64);
    if (lane == 0) out[wave] = p * (1.0f / 16.0f);
}

// ---------------------------------------------------------------------------

extern "C" void kernel_launch(void* const* d_in, const int* in_sizes, int n_in,
                              void* d_out, int out_size, void* d_ws, size_t ws_size,
                              hipStream_t stream) {
    const int*   users    = (const int*)  d_in[0];
    const int*   items    = (const int*)  d_in[1];
    const int*   adj_rows = (const int*)  d_in[2];
    const int*   adj_cols = (const int*)  d_in[3];
    const float* adj_vals = (const float*)d_in[4];
    const float* user_emb = (const float*)d_in[5];
    const float* item_emb = (const float*)d_in[6];
    float* out = (float*)d_out;

    const int batch = in_sizes[0];
    const int nnz   = in_sizes[2];

    // workspace layout (256B aligned slices)
    char* p = (char*)d_ws;
    auto alloc = [&](size_t bytes) -> char* {
        char* r = p;
        p += (bytes + 255) & ~(size_t)255;
        return r;
    };
    int*   counts     = (int*)  alloc((size_t)N_NODES * 4);        // reused as fill cursor
    int*   offs       = (int*)  alloc(((size_t)N_NODES + 1) * 4);
    int*   block_sums = (int*)  alloc(256 * 4);
    int*   block_base = (int*)  alloc(256 * 4);
    int*   csr_col    = (int*)  alloc((size_t)nnz * 4);
    float* csr_val    = (float*)alloc((size_t)nnz * 4);
    float* bufA       = (float*)alloc((size_t)N_NODES * EMBED_DIM * 4);
    float* bufB       = (float*)alloc((size_t)N_NODES * EMBED_DIM * 4);
    float* u_acc      = (float*)alloc((size_t)batch * EMBED_DIM * 4);
    float* i_acc      = (float*)alloc((size_t)batch * EMBED_DIM * 4);

    const int nb_scan = (N_NODES + SCAN_CHUNK - 1) / SCAN_CHUNK;   // 74
    const int g_nnz   = (nnz + 255) / 256;
    const int g_nodes = (N_NODES * 64 + 255) / 256;                // 4 rows (waves) / block
    const int g_batch = (batch * 64 + 255) / 256;

    // ---- CSR build ----
    hipMemsetAsync(counts, 0, (size_t)N_NODES * 4, stream);
    k_hist<<<g_nnz, 256, 0, stream>>>(adj_rows, counts, nnz);
    k_scan1<<<nb_scan, 256, 0, stream>>>(counts, offs, block_sums, N_NODES);
    k_scan2<<<1, 64, 0, stream>>>(block_sums, block_base, nb_scan);
    k_addbase<<<(N_NODES + 255) / 256, 256, 0, stream>>>(offs, block_base, N_NODES, nnz);
    hipMemsetAsync(counts, 0, (size_t)N_NODES * 4, stream);        // -> fill cursors
    k_scatter<<<g_nnz, 256, 0, stream>>>(adj_rows, adj_cols, adj_vals, offs,
                                         counts, csr_col, csr_val, nnz);

    // ---- layer 0 (ego) contribution to batch accumulators ----
    k_gather<<<g_batch, 256, 0, stream>>>(users, items, user_emb, item_emb,
                                          NUM_USERS, u_acc, i_acc, /*add=*/0, batch);

    // ---- layer 1: cur1 = A * ego ----
    k_spmm<<<g_nodes, 256, 0, stream>>>(offs, csr_col, csr_val,
                                        user_emb, item_emb, NUM_USERS, bufA);
    k_gather<<<g_batch, 256, 0, stream>>>(users, items, bufA, bufA, 0,
                                          u_acc, i_acc, 1, batch);

    // ---- layer 2: cur2 = A * cur1 ----
    k_spmm<<<g_nodes, 256, 0, stream>>>(offs, csr_col, csr_val,
                                        bufA, bufA, 0, bufB);
    k_gather<<<g_batch, 256, 0, stream>>>(users, items, bufB, bufB, 0,
                                          u_acc, i_acc, 1, batch);

    // ---- layer 3: cur3 = A * cur2 ----
    k_spmm<<<g_nodes, 256, 0, stream>>>(offs, csr_col, csr_val,
                                        bufB, bufB, 0, bufA);
    k_gather<<<g_batch, 256, 0, stream>>>(users, items, bufA, bufA, 0,
                                          u_acc, i_acc, 1, batch);

    // ---- final dot ----
    k_dot<<<g_batch, 256, 0, stream>>>(u_acc, i_acc, out, batch);
}

// Round 2
// 1011.318 us; speedup vs baseline: 1.9245x; 1.9245x over previous
//
#include <hip/hip_runtime.h>

#define NUM_USERS 100000
#define NUM_ITEMS 50000
#define EMBED_DIM 64
#define N_NODES   150000   // NUM_USERS + NUM_ITEMS
#define SCAN_CHUNK 2048    // 256 threads x 8 elems

// ---------------------------------------------------------------------------
// CSR build: histogram -> scan -> scatter (packed int2 {col, bitcast(val)})
// ---------------------------------------------------------------------------

__global__ void k_hist(const int* __restrict__ rows, int* __restrict__ counts, int nnz) {
    int i = blockIdx.x * blockDim.x + threadIdx.x;
    if (i < nnz) atomicAdd(&counts[rows[i]], 1);
}

__global__ void k_scan1(const int* __restrict__ counts, int* __restrict__ offs,
                        int* __restrict__ block_sums, int n) {
    __shared__ int lds[256];
    int base = blockIdx.x * SCAN_CHUNK;
    int vals[8];
    int sum = 0;
#pragma unroll
    for (int j = 0; j < 8; j++) {
        int idx = base + threadIdx.x * 8 + j;
        int v = (idx < n) ? counts[idx] : 0;
        vals[j] = sum;
        sum += v;
    }
    lds[threadIdx.x] = sum;
    __syncthreads();
    for (int d = 1; d < 256; d <<= 1) {
        int y = (threadIdx.x >= (unsigned)d) ? lds[threadIdx.x - d] : 0;
        __syncthreads();
        lds[threadIdx.x] += y;
        __syncthreads();
    }
    int excl = lds[threadIdx.x] - sum;
#pragma unroll
    for (int j = 0; j < 8; j++) {
        int idx = base + threadIdx.x * 8 + j;
        if (idx < n) offs[idx] = excl + vals[j];
    }
    if (threadIdx.x == 0) block_sums[blockIdx.x] = lds[255];
}

// single-block LDS scan of the (<=128) chunk totals — replaces serial loop
__global__ void k_scan2(const int* __restrict__ block_sums, int* __restrict__ block_base, int nb) {
    __shared__ int lds[128];
    int v = (threadIdx.x < (unsigned)nb) ? block_sums[threadIdx.x] : 0;
    lds[threadIdx.x] = v;
    __syncthreads();
    for (int d = 1; d < 128; d <<= 1) {
        int y = (threadIdx.x >= (unsigned)d) ? lds[threadIdx.x - d] : 0;
        __syncthreads();
        lds[threadIdx.x] += y;
        __syncthreads();
    }
    if (threadIdx.x < (unsigned)nb) block_base[threadIdx.x] = lds[threadIdx.x] - v; // exclusive
}

// finalize offs and initialize scatter cursors in one pass
__global__ void k_addbase(int* __restrict__ offs, int* __restrict__ cursor,
                          const int* __restrict__ block_base, int n, int total) {
    int i = blockIdx.x * blockDim.x + threadIdx.x;
    if (i < n) {
        int v = offs[i] + block_base[i >> 11];  // 2048 = 1<<11
        offs[i] = v;
        cursor[i] = v;
    }
    if (i == 0) offs[n] = total;
}

__global__ void k_scatter(const int* __restrict__ rows, const int* __restrict__ cols,
                          const float* __restrict__ vals, int* __restrict__ cursor,
                          int2* __restrict__ cv, int nnz) {
    int i = blockIdx.x * blockDim.x + threadIdx.x;
    if (i < nnz) {
        int r = rows[i];
        int pos = atomicAdd(&cursor[r], 1);
        cv[pos] = make_int2(cols[i], __float_as_int(vals[i]));  // one 8B store
    }
}

// ---------------------------------------------------------------------------
// SpMM row body: one wave per row, lane = embedding dim, edge loop unrolled x8
// so 8 gathers (plus 8 cv loads) are in flight per wave.
// ---------------------------------------------------------------------------
__device__ __forceinline__ float spmm_row(int beg, int end, int lane,
                                          const int2* __restrict__ cv,
                                          const float* __restrict__ x_lo,
                                          const float* __restrict__ x_hi,
                                          int split) {
    float acc = 0.f;
    int e = beg;
#pragma unroll 1
    for (; e + 8 <= end; e += 8) {
        int2 c[8];
        float xv[8];
#pragma unroll
        for (int j = 0; j < 8; j++) c[j] = cv[e + j];
#pragma unroll
        for (int j = 0; j < 8; j++) {
            int col = c[j].x;
            const float* xr = (col < split) ? (x_lo + (size_t)col * EMBED_DIM)
                                            : (x_hi + (size_t)(col - split) * EMBED_DIM);
            xv[j] = xr[lane];
        }
#pragma unroll
        for (int j = 0; j < 8; j++) acc += __int_as_float(c[j].y) * xv[j];
    }
#pragma unroll 1
    for (; e < end; e++) {
        int2 c = cv[e];
        int col = c.x;
        const float* xr = (col < split) ? (x_lo + (size_t)col * EMBED_DIM)
                                        : (x_hi + (size_t)(col - split) * EMBED_DIM);
        acc += __int_as_float(c.y) * xr[lane];
    }
    return acc;
}

__global__ void k_spmm(const int* __restrict__ offs, const int2* __restrict__ cv,
                       const float* __restrict__ x_lo, const float* __restrict__ x_hi,
                       int split, float* __restrict__ out) {
    int row = (blockIdx.x * blockDim.x + threadIdx.x) >> 6;
    int lane = threadIdx.x & 63;
    if (row >= N_NODES) return;
    int beg = offs[row], end = offs[row + 1];
    float acc = spmm_row(beg, end, lane, cv, x_lo, x_hi, split);
    out[(size_t)row * EMBED_DIM + lane] = acc;
}

// Last layer: only the batch's rows are ever consumed — compute just those
// (2*BATCH = 32768 row-dots vs 150000) and accumulate straight into u/i_acc.
__global__ void k_spmm_batch(const int* __restrict__ offs, const int2* __restrict__ cv,
                             const float* __restrict__ x,
                             const int* __restrict__ users, const int* __restrict__ items,
                             float* __restrict__ u_acc, float* __restrict__ i_acc,
                             int batch) {
    int w = (blockIdx.x * blockDim.x + threadIdx.x) >> 6;
    int lane = threadIdx.x & 63;
    if (w >= 2 * batch) return;
    int b, row;
    float* dst;
    if (w < batch) { b = w;         row = users[b];             dst = u_acc; }
    else           { b = w - batch; row = NUM_USERS + items[b]; dst = i_acc; }
    int beg = offs[row], end = offs[row + 1];
    float acc = spmm_row(beg, end, lane, cv, x, x, 0);
    dst[(size_t)b * EMBED_DIM + lane] += acc;
}

// ---------------------------------------------------------------------------
// Accumulate the batch's user/item rows of the current layer into u_acc/i_acc.
// ---------------------------------------------------------------------------
__global__ void k_gather(const int* __restrict__ users, const int* __restrict__ items,
                         const float* __restrict__ x_lo, const float* __restrict__ x_hi,
                         int split, float* __restrict__ u_acc, float* __restrict__ i_acc,
                         int add, int batch) {
    int wave = (blockIdx.x * blockDim.x + threadIdx.x) >> 6;
    int lane = threadIdx.x & 63;
    if (wave >= batch) return;
    int nu = users[wave];
    int ni = NUM_USERS + items[wave];
    const float* ur = (nu < split) ? (x_lo + (size_t)nu * EMBED_DIM)
                                   : (x_hi + (size_t)(nu - split) * EMBED_DIM);
    const float* ir = (ni < split) ? (x_lo + (size_t)ni * EMBED_DIM)
                                   : (x_hi + (size_t)(ni - split) * EMBED_DIM);
    float uv = ur[lane];
    float iv = ir[lane];
    size_t o = (size_t)wave * EMBED_DIM + lane;
    if (add) { u_acc[o] += uv; i_acc[o] += iv; }
    else     { u_acc[o]  = uv; i_acc[o]  = iv; }
}

// out[b] = dot(u_acc[b], i_acc[b]) / 16   (mean = acc/4 on each side)
__global__ void k_dot(const float* __restrict__ u_acc, const float* __restrict__ i_acc,
                      float* __restrict__ out, int batch) {
    int wave = (blockIdx.x * blockDim.x + threadIdx.x) >> 6;
    int lane = threadIdx.x & 63;
    if (wave >= batch) return;
    size_t o = (size_t)wave * EMBED_DIM + lane;
    float p = u_acc[o] * i_acc[o];
#pragma unroll
    for (int d = 32; d > 0; d >>= 1) p += __shfl_down(p, d, 64);
    if (lane == 0) out[wave] = p * (1.0f / 16.0f);
}

// ---------------------------------------------------------------------------

extern "C" void kernel_launch(void* const* d_in, const int* in_sizes, int n_in,
                              void* d_out, int out_size, void* d_ws, size_t ws_size,
                              hipStream_t stream) {
    const int*   users    = (const int*)  d_in[0];
    const int*   items    = (const int*)  d_in[1];
    const int*   adj_rows = (const int*)  d_in[2];
    const int*   adj_cols = (const int*)  d_in[3];
    const float* adj_vals = (const float*)d_in[4];
    const float* user_emb = (const float*)d_in[5];
    const float* item_emb = (const float*)d_in[6];
    float* out = (float*)d_out;

    const int batch = in_sizes[0];
    const int nnz   = in_sizes[2];

    char* p = (char*)d_ws;
    auto alloc = [&](size_t bytes) -> char* {
        char* r = p;
        p += (bytes + 255) & ~(size_t)255;
        return r;
    };
    int*   counts     = (int*)  alloc((size_t)N_NODES * 4);   // hist
    int*   cursor     = (int*)  alloc((size_t)N_NODES * 4);   // scatter cursors
    int*   offs       = (int*)  alloc(((size_t)N_NODES + 1) * 4);
    int*   block_sums = (int*)  alloc(256 * 4);
    int*   block_base = (int*)  alloc(256 * 4);
    int2*  cv         = (int2*) alloc((size_t)nnz * 8);       // packed (col,val)
    float* bufA       = (float*)alloc((size_t)N_NODES * EMBED_DIM * 4);
    float* bufB       = (float*)alloc((size_t)N_NODES * EMBED_DIM * 4);
    float* u_acc      = (float*)alloc((size_t)batch * EMBED_DIM * 4);
    float* i_acc      = (float*)alloc((size_t)batch * EMBED_DIM * 4);

    const int nb_scan = (N_NODES + SCAN_CHUNK - 1) / SCAN_CHUNK;   // 74
    const int g_nnz   = (nnz + 255) / 256;
    const int g_nodes = (N_NODES + 3) / 4;          // 4 rows (waves) / block
    const int g_batch = (batch + 3) / 4;
    const int g_batch2 = (2 * batch + 3) / 4;

    // ---- CSR build ----
    hipMemsetAsync(counts, 0, (size_t)N_NODES * 4, stream);
    k_hist<<<g_nnz, 256, 0, stream>>>(adj_rows, counts, nnz);
    k_scan1<<<nb_scan, 256, 0, stream>>>(counts, offs, block_sums, N_NODES);
    k_scan2<<<1, 128, 0, stream>>>(block_sums, block_base, nb_scan);
    k_addbase<<<(N_NODES + 255) / 256, 256, 0, stream>>>(offs, cursor, block_base, N_NODES, nnz);
    k_scatter<<<g_nnz, 256, 0, stream>>>(adj_rows, adj_cols, adj_vals, cursor, cv, nnz);

    // ---- layer 0 (ego) contribution ----
    k_gather<<<g_batch, 256, 0, stream>>>(users, items, user_emb, item_emb,
                                          NUM_USERS, u_acc, i_acc, /*add=*/0, batch);

    // ---- layer 1: cur1 = A * ego ----
    k_spmm<<<g_nodes, 256, 0, stream>>>(offs, cv, user_emb, item_emb, NUM_USERS, bufA);
    k_gather<<<g_batch, 256, 0, stream>>>(users, items, bufA, bufA, 0,
                                          u_acc, i_acc, 1, batch);

    // ---- layer 2: cur2 = A * cur1 ----
    k_spmm<<<g_nodes, 256, 0, stream>>>(offs, cv, bufA, bufA, 0, bufB);
    k_gather<<<g_batch, 256, 0, stream>>>(users, items, bufB, bufB, 0,
                                          u_acc, i_acc, 1, batch);

    // ---- layer 3: only batch rows needed — fused spmm+gather ----
    k_spmm_batch<<<g_batch2, 256, 0, stream>>>(offs, cv, bufB, users, items,
                                               u_acc, i_acc, batch);

    // ---- final dot ----
    k_dot<<<g_batch, 256, 0, stream>>>(u_acc, i_acc, out, batch);
}

// Round 3
// 693.936 us; speedup vs baseline: 2.8046x; 1.4574x over previous
//
#include <hip/hip_runtime.h>

#define NUM_USERS 100000
#define NUM_ITEMS 50000
#define EMBED_DIM 64
#define N_NODES   150000                 // NUM_USERS + NUM_ITEMS
#define ROW_SHIFT 10                     // 1024 rows per bucket
#define ROWS_PER_BUCKET 1024
#define B_BUCKETS ((N_NODES + ROWS_PER_BUCKET - 1) / ROWS_PER_BUCKET)   // 147
#define BIN_CHUNK 2048                   // edges per k_bin block (8/thread)

// ---------------------------------------------------------------------------
// Pass 0: coarse bucket histogram (147 counters) via per-block LDS hist.
// ---------------------------------------------------------------------------
__global__ void k_bucket_hist(const int* __restrict__ rows, int* __restrict__ bhist, int nnz) {
    __shared__ int lh[256];
    int t = threadIdx.x;
    lh[t] = 0;
    __syncthreads();
    int base = blockIdx.x * (256 * 32);
#pragma unroll
    for (int k = 0; k < 32; k++) {
        int idx = base + k * 256 + t;
        if (idx < nnz) atomicAdd(&lh[rows[idx] >> ROW_SHIFT], 1);
    }
    __syncthreads();
    if (t < B_BUCKETS && lh[t] > 0) atomicAdd(&bhist[t], lh[t]);
}

// Pass 0b: single-block scan of 147 bucket counts -> bucket_off (excl, +total),
// bucket_cursor init, offs[N_NODES] sentinel.
__global__ void k_bucket_scan(const int* __restrict__ bhist, int* __restrict__ bucket_off,
                              int* __restrict__ bucket_cursor, int* __restrict__ offs, int nnz) {
    __shared__ int lds[256];
    int t = threadIdx.x;
    int v = (t < B_BUCKETS) ? bhist[t] : 0;
    lds[t] = v;
    __syncthreads();
    for (int d = 1; d < 256; d <<= 1) {
        int y = (t >= d) ? lds[t - d] : 0;
        __syncthreads();
        lds[t] += y;
        __syncthreads();
    }
    int excl = lds[t] - v;
    if (t < B_BUCKETS) {
        bucket_off[t] = excl;
        bucket_cursor[t] = excl;
    }
    if (t == 0) {
        bucket_off[B_BUCKETS] = nnz;
        offs[N_NODES] = nnz;
    }
}

// ---------------------------------------------------------------------------
// Pass 1: LDS-binned staging. Each block takes BIN_CHUNK edges, groups them by
// bucket in LDS, then flushes per-bucket CONTIGUOUS runs to the staging array
// (full-cache-line writes instead of 8B random scatter).
// Staging entry: int4 (row, col, bitcast(val), bucket).
// ---------------------------------------------------------------------------
__global__ void __launch_bounds__(256) k_bin(const int* __restrict__ rows,
                                             const int* __restrict__ cols,
                                             const float* __restrict__ vals,
                                             int* __restrict__ bucket_cursor,
                                             int4* __restrict__ staging, int nnz) {
    __shared__ int  ccnt[256];           // per-bucket count in this chunk (preserved)
    __shared__ int  cpos[256];           // scan temp -> running cursor
    __shared__ int  gdst[256];           // global dest base minus local run base
    __shared__ int4 entries[BIN_CHUNK];  // 32 KB

    int t = threadIdx.x;
    int base = blockIdx.x * BIN_CHUNK;
    ccnt[t] = 0;
    __syncthreads();

    int myrow[BIN_CHUNK / 256];
#pragma unroll
    for (int k = 0; k < BIN_CHUNK / 256; k++) {
        int idx = base + k * 256 + t;
        int r = (idx < nnz) ? rows[idx] : -1;
        myrow[k] = r;
        if (r >= 0) atomicAdd(&ccnt[r >> ROW_SHIFT], 1);
    }
    __syncthreads();

    // inclusive scan of per-bucket counts
    int c = ccnt[t];
    cpos[t] = c;
    __syncthreads();
    for (int d = 1; d < 256; d <<= 1) {
        int y = (t >= d) ? cpos[t - d] : 0;
        __syncthreads();
        cpos[t] += y;
        __syncthreads();
    }
    int total = cpos[255];               // valid edges in this chunk
    int excl = cpos[t] - c;
    __syncthreads();
    cpos[t] = excl;                      // becomes local cursor
    __syncthreads();

    // place entries grouped by bucket
#pragma unroll
    for (int k = 0; k < BIN_CHUNK / 256; k++) {
        int r = myrow[k];
        if (r >= 0) {
            int idx = base + k * 256 + t;
            int b = r >> ROW_SHIFT;
            int slot = atomicAdd(&cpos[b], 1);
            entries[slot] = make_int4(r, cols[idx], __float_as_int(vals[idx]), b);
        }
    }
    __syncthreads();

    // reserve global space per bucket (cpos[t] is now inclusive again)
    if (t < B_BUCKETS && ccnt[t] > 0) {
        int g = atomicAdd(&bucket_cursor[t], ccnt[t]);
        gdst[t] = g - (cpos[t] - ccnt[t]);
    }
    __syncthreads();

    // flush: consecutive i within a run -> consecutive global addresses
    for (int i = t; i < total; i += 256) {
        int4 e = entries[i];
        staging[gdst[e.w] + i] = e;
    }
}

// ---------------------------------------------------------------------------
// Pass 2: one block OWNS one bucket (1024 rows). Per-row LDS count -> LDS scan
// -> write offs + scatter cv within the block's private region. All writes of
// each cache line come from one block/XCD -> full-line evictions.
// ---------------------------------------------------------------------------
__global__ void __launch_bounds__(1024) k_scatter2(const int4* __restrict__ staging,
                                                   const int* __restrict__ bucket_off,
                                                   int* __restrict__ offs,
                                                   int2* __restrict__ cv) {
    __shared__ int rc[ROWS_PER_BUCKET];
    int b = blockIdx.x;
    int t = threadIdx.x;
    int beg = bucket_off[b], end = bucket_off[b + 1];
    int row0 = b << ROW_SHIFT;

    rc[t] = 0;
    __syncthreads();
    for (int i = beg + t; i < end; i += 1024)
        atomicAdd(&rc[staging[i].x - row0], 1);
    __syncthreads();

    int c = rc[t];
    for (int d = 1; d < 1024; d <<= 1) {
        int y = (t >= d) ? rc[t - d] : 0;
        __syncthreads();
        rc[t] += y;
        __syncthreads();
    }
    int excl = rc[t] - c;
    int row = row0 + t;
    if (row < N_NODES) offs[row] = beg + excl;
    __syncthreads();
    rc[t] = excl;                        // becomes per-row cursor
    __syncthreads();

    for (int i = beg + t; i < end; i += 1024) {
        int4 e = staging[i];
        int pos = beg + atomicAdd(&rc[e.x - row0], 1);
        cv[pos] = make_int2(e.y, e.z);
    }
}

// ---------------------------------------------------------------------------
// SpMM row body: one wave per row, lane = embedding dim, edge loop unrolled x8.
// ---------------------------------------------------------------------------
__device__ __forceinline__ float spmm_row(int beg, int end, int lane,
                                          const int2* __restrict__ cv,
                                          const float* __restrict__ x_lo,
                                          const float* __restrict__ x_hi,
                                          int split) {
    float acc = 0.f;
    int e = beg;
#pragma unroll 1
    for (; e + 8 <= end; e += 8) {
        int2 c[8];
        float xv[8];
#pragma unroll
        for (int j = 0; j < 8; j++) c[j] = cv[e + j];
#pragma unroll
        for (int j = 0; j < 8; j++) {
            int col = c[j].x;
            const float* xr = (col < split) ? (x_lo + (size_t)col * EMBED_DIM)
                                            : (x_hi + (size_t)(col - split) * EMBED_DIM);
            xv[j] = xr[lane];
        }
#pragma unroll
        for (int j = 0; j < 8; j++) acc += __int_as_float(c[j].y) * xv[j];
    }
#pragma unroll 1
    for (; e < end; e++) {
        int2 c = cv[e];
        int col = c.x;
        const float* xr = (col < split) ? (x_lo + (size_t)col * EMBED_DIM)
                                        : (x_hi + (size_t)(col - split) * EMBED_DIM);
        acc += __int_as_float(c.y) * xr[lane];
    }
    return acc;
}

__global__ void k_spmm(const int* __restrict__ offs, const int2* __restrict__ cv,
                       const float* __restrict__ x_lo, const float* __restrict__ x_hi,
                       int split, float* __restrict__ out) {
    int row = (blockIdx.x * blockDim.x + threadIdx.x) >> 6;
    int lane = threadIdx.x & 63;
    if (row >= N_NODES) return;
    int beg = offs[row], end = offs[row + 1];
    float acc = spmm_row(beg, end, lane, cv, x_lo, x_hi, split);
    out[(size_t)row * EMBED_DIM + lane] = acc;
}

// Last layer: only batch rows are consumed — compute just those.
__global__ void k_spmm_batch(const int* __restrict__ offs, const int2* __restrict__ cv,
                             const float* __restrict__ x,
                             const int* __restrict__ users, const int* __restrict__ items,
                             float* __restrict__ u_acc, float* __restrict__ i_acc,
                             int batch) {
    int w = (blockIdx.x * blockDim.x + threadIdx.x) >> 6;
    int lane = threadIdx.x & 63;
    if (w >= 2 * batch) return;
    int b, row;
    float* dst;
    if (w < batch) { b = w;         row = users[b];             dst = u_acc; }
    else           { b = w - batch; row = NUM_USERS + items[b]; dst = i_acc; }
    int beg = offs[row], end = offs[row + 1];
    float acc = spmm_row(beg, end, lane, cv, x, x, 0);
    dst[(size_t)b * EMBED_DIM + lane] += acc;
}

// ---------------------------------------------------------------------------
__global__ void k_gather(const int* __restrict__ users, const int* __restrict__ items,
                         const float* __restrict__ x_lo, const float* __restrict__ x_hi,
                         int split, float* __restrict__ u_acc, float* __restrict__ i_acc,
                         int add, int batch) {
    int wave = (blockIdx.x * blockDim.x + threadIdx.x) >> 6;
    int lane = threadIdx.x & 63;
    if (wave >= batch) return;
    int nu = users[wave];
    int ni = NUM_USERS + items[wave];
    const float* ur = (nu < split) ? (x_lo + (size_t)nu * EMBED_DIM)
                                   : (x_hi + (size_t)(nu - split) * EMBED_DIM);
    const float* ir = (ni < split) ? (x_lo + (size_t)ni * EMBED_DIM)
                                   : (x_hi + (size_t)(ni - split) * EMBED_DIM);
    float uv = ur[lane];
    float iv = ir[lane];
    size_t o = (size_t)wave * EMBED_DIM + lane;
    if (add) { u_acc[o] += uv; i_acc[o] += iv; }
    else     { u_acc[o]  = uv; i_acc[o]  = iv; }
}

__global__ void k_dot(const float* __restrict__ u_acc, const float* __restrict__ i_acc,
                      float* __restrict__ out, int batch) {
    int wave = (blockIdx.x * blockDim.x + threadIdx.x) >> 6;
    int lane = threadIdx.x & 63;
    if (wave >= batch) return;
    size_t o = (size_t)wave * EMBED_DIM + lane;
    float p = u_acc[o] * i_acc[o];
#pragma unroll
    for (int d = 32; d > 0; d >>= 1) p += __shfl_down(p, d, 64);
    if (lane == 0) out[wave] = p * (1.0f / 16.0f);
}

// ---------------------------------------------------------------------------

extern "C" void kernel_launch(void* const* d_in, const int* in_sizes, int n_in,
                              void* d_out, int out_size, void* d_ws, size_t ws_size,
                              hipStream_t stream) {
    const int*   users    = (const int*)  d_in[0];
    const int*   items    = (const int*)  d_in[1];
    const int*   adj_rows = (const int*)  d_in[2];
    const int*   adj_cols = (const int*)  d_in[3];
    const float* adj_vals = (const float*)d_in[4];
    const float* user_emb = (const float*)d_in[5];
    const float* item_emb = (const float*)d_in[6];
    float* out = (float*)d_out;

    const int batch = in_sizes[0];
    const int nnz   = in_sizes[2];

    char* p = (char*)d_ws;
    auto alloc = [&](size_t bytes) -> char* {
        char* r = p;
        p += (bytes + 255) & ~(size_t)255;
        return r;
    };
    int*   offs          = (int*)  alloc(((size_t)N_NODES + 1) * 4);
    int*   bhist         = (int*)  alloc(256 * 4);
    int*   bucket_off    = (int*)  alloc(256 * 4);
    int*   bucket_cursor = (int*)  alloc(256 * 4);
    int2*  cv            = (int2*) alloc((size_t)nnz * 8);            // final CSR (col,val)
    // bufA+bufB region doubles as the int4 staging array (dead before spmm1):
    float* bufA          = (float*)alloc(2 * (size_t)N_NODES * EMBED_DIM * 4);
    float* bufB          = bufA + (size_t)N_NODES * EMBED_DIM;
    int4*  staging       = (int4*)bufA;                               // nnz*16 = 76.8 MB fits
    float* u_acc         = (float*)alloc((size_t)batch * EMBED_DIM * 4);
    float* i_acc         = (float*)alloc((size_t)batch * EMBED_DIM * 4);

    const int g_bhist  = (nnz + 256 * 32 - 1) / (256 * 32);
    const int g_bin    = (nnz + BIN_CHUNK - 1) / BIN_CHUNK;
    const int g_nodes  = (N_NODES + 3) / 4;          // 4 rows (waves) / 256-thr block
    const int g_batch  = (batch + 3) / 4;
    const int g_batch2 = (2 * batch + 3) / 4;

    // ---- CSR build (bucket-staged counting sort) ----
    hipMemsetAsync(bhist, 0, 256 * 4, stream);
    k_bucket_hist<<<g_bhist, 256, 0, stream>>>(adj_rows, bhist, nnz);
    k_bucket_scan<<<1, 256, 0, stream>>>(bhist, bucket_off, bucket_cursor, offs, nnz);
    k_bin<<<g_bin, 256, 0, stream>>>(adj_rows, adj_cols, adj_vals, bucket_cursor, staging, nnz);
    k_scatter2<<<B_BUCKETS, 1024, 0, stream>>>(staging, bucket_off, offs, cv);

    // ---- layer 0 (ego) contribution ----
    k_gather<<<g_batch, 256, 0, stream>>>(users, items, user_emb, item_emb,
                                          NUM_USERS, u_acc, i_acc, /*add=*/0, batch);

    // ---- layer 1: cur1 = A * ego ----
    k_spmm<<<g_nodes, 256, 0, stream>>>(offs, cv, user_emb, item_emb, NUM_USERS, bufA);
    k_gather<<<g_batch, 256, 0, stream>>>(users, items, bufA, bufA, 0,
                                          u_acc, i_acc, 1, batch);

    // ---- layer 2: cur2 = A * cur1 ----
    k_spmm<<<g_nodes, 256, 0, stream>>>(offs, cv, bufA, bufA, 0, bufB);
    k_gather<<<g_batch, 256, 0, stream>>>(users, items, bufB, bufB, 0,
                                          u_acc, i_acc, 1, batch);

    // ---- layer 3: only batch rows needed — fused spmm+gather ----
    k_spmm_batch<<<g_batch2, 256, 0, stream>>>(offs, cv, bufB, users, items,
                                               u_acc, i_acc, batch);

    // ---- final dot ----
    k_dot<<<g_batch, 256, 0, stream>>>(u_acc, i_acc, out, batch);
}

// Round 4
// 642.313 us; speedup vs baseline: 3.0301x; 1.0804x over previous
//
#include <hip/hip_runtime.h>

#define NUM_USERS 100000
#define NUM_ITEMS 50000
#define EMBED_DIM 64
#define N_NODES   150000                 // NUM_USERS + NUM_ITEMS
#define ROW_SHIFT 10                     // 1024 rows per bucket
#define ROWS_PER_BUCKET 1024
#define B_BUCKETS ((N_NODES + ROWS_PER_BUCKET - 1) / ROWS_PER_BUCKET)   // 147
#define BIN_CHUNK 2048                   // edges per k_bin block (8/thread)
#define COL_MASK 0x3FFFF                 // 18 bits for col (N_NODES < 262144)

// ---------------------------------------------------------------------------
// Pass 0: coarse bucket histogram (147 counters) via per-block LDS hist.
// ---------------------------------------------------------------------------
__global__ void k_bucket_hist(const int* __restrict__ rows, int* __restrict__ bhist, int nnz) {
    __shared__ int lh[256];
    int t = threadIdx.x;
    lh[t] = 0;
    __syncthreads();
    int base = blockIdx.x * (256 * 32);
#pragma unroll
    for (int k = 0; k < 32; k++) {
        int idx = base + k * 256 + t;
        if (idx < nnz) atomicAdd(&lh[rows[idx] >> ROW_SHIFT], 1);
    }
    __syncthreads();
    if (t < B_BUCKETS && lh[t] > 0) atomicAdd(&bhist[t], lh[t]);
}

// Pass 0b: single-block scan of bucket counts -> bucket_off, cursors, sentinel.
__global__ void k_bucket_scan(const int* __restrict__ bhist, int* __restrict__ bucket_off,
                              int* __restrict__ bucket_cursor, int* __restrict__ offs, int nnz) {
    __shared__ int lds[256];
    int t = threadIdx.x;
    int v = (t < B_BUCKETS) ? bhist[t] : 0;
    lds[t] = v;
    __syncthreads();
    for (int d = 1; d < 256; d <<= 1) {
        int y = (t >= d) ? lds[t - d] : 0;
        __syncthreads();
        lds[t] += y;
        __syncthreads();
    }
    int excl = lds[t] - v;
    if (t < B_BUCKETS) {
        bucket_off[t] = excl;
        bucket_cursor[t] = excl;
    }
    if (t == 0) {
        bucket_off[B_BUCKETS] = nnz;
        offs[N_NODES] = nnz;
    }
}

// ---------------------------------------------------------------------------
// Pass 1: LDS-binned staging, packed int2 {col | lrow<<18, val} + uint8 bucket.
// Flushes per-bucket contiguous runs (full-line writes, bucket-major layout).
// ---------------------------------------------------------------------------
__global__ void __launch_bounds__(256) k_bin(const int* __restrict__ rows,
                                             const int* __restrict__ cols,
                                             const float* __restrict__ vals,
                                             int* __restrict__ bucket_cursor,
                                             int2* __restrict__ staging, int nnz) {
    __shared__ int  ccnt[256];
    __shared__ int  cpos[256];
    __shared__ int  gdst[256];
    __shared__ int2 entries[BIN_CHUNK];            // 16 KB
    __shared__ unsigned char ebuck[BIN_CHUNK];     // 2 KB

    int t = threadIdx.x;
    int base = blockIdx.x * BIN_CHUNK;
    ccnt[t] = 0;
    __syncthreads();

    int myrow[BIN_CHUNK / 256];
#pragma unroll
    for (int k = 0; k < BIN_CHUNK / 256; k++) {
        int idx = base + k * 256 + t;
        int r = (idx < nnz) ? rows[idx] : -1;
        myrow[k] = r;
        if (r >= 0) atomicAdd(&ccnt[r >> ROW_SHIFT], 1);
    }
    __syncthreads();

    int c = ccnt[t];
    cpos[t] = c;
    __syncthreads();
    for (int d = 1; d < 256; d <<= 1) {
        int y = (t >= d) ? cpos[t - d] : 0;
        __syncthreads();
        cpos[t] += y;
        __syncthreads();
    }
    int total = cpos[255];
    int excl = cpos[t] - c;
    __syncthreads();
    cpos[t] = excl;
    __syncthreads();

#pragma unroll
    for (int k = 0; k < BIN_CHUNK / 256; k++) {
        int r = myrow[k];
        if (r >= 0) {
            int idx = base + k * 256 + t;
            int b = r >> ROW_SHIFT;
            int lrow = r & (ROWS_PER_BUCKET - 1);
            int slot = atomicAdd(&cpos[b], 1);
            entries[slot] = make_int2(cols[idx] | (lrow << 18), __float_as_int(vals[idx]));
            ebuck[slot] = (unsigned char)b;
        }
    }
    __syncthreads();

    if (t < B_BUCKETS && ccnt[t] > 0) {
        int g = atomicAdd(&bucket_cursor[t], ccnt[t]);
        gdst[t] = g - (cpos[t] - ccnt[t]);
    }
    __syncthreads();

    for (int i = t; i < total; i += 256) {
        staging[gdst[ebuck[i]] + i] = entries[i];
    }
}

// ---------------------------------------------------------------------------
// Pass 2: one block owns one bucket (1024 rows). Count -> scan -> scatter,
// all writes of each cv cache line come from one block.
// ---------------------------------------------------------------------------
__global__ void __launch_bounds__(1024) k_scatter2(const int2* __restrict__ staging,
                                                   const int* __restrict__ bucket_off,
                                                   int* __restrict__ offs,
                                                   int2* __restrict__ cv) {
    __shared__ int rc[ROWS_PER_BUCKET];
    int b = blockIdx.x;
    int t = threadIdx.x;
    int beg = bucket_off[b], end = bucket_off[b + 1];
    int row0 = b << ROW_SHIFT;

    rc[t] = 0;
    __syncthreads();
    for (int i = beg + t; i < end; i += 1024)
        atomicAdd(&rc[staging[i].x >> 18], 1);
    __syncthreads();

    int c = rc[t];
    for (int d = 1; d < 1024; d <<= 1) {
        int y = (t >= d) ? rc[t - d] : 0;
        __syncthreads();
        rc[t] += y;
        __syncthreads();
    }
    int excl = rc[t] - c;
    int row = row0 + t;
    if (row < N_NODES) offs[row] = beg + excl;
    __syncthreads();
    rc[t] = excl;
    __syncthreads();

    for (int i = beg + t; i < end; i += 1024) {
        int2 e = staging[i];
        int pos = beg + atomicAdd(&rc[e.x >> 18], 1);
        cv[pos] = make_int2(e.x & COL_MASK, e.y);
    }
}

// ---------------------------------------------------------------------------
// SpMM row body: one wave per row, lane = embedding dim. The edge stream is
// wave-uniform: readfirstlane everything except the gather + FMA so the
// cv loads scalarize (s_load) and addressing moves to the scalar pipe.
// ---------------------------------------------------------------------------
__device__ __forceinline__ float spmm_row(int beg, int end, int lane,
                                          const int2* __restrict__ cv,
                                          const float* __restrict__ x_lo,
                                          const float* __restrict__ x_hi,
                                          int split) {
    float acc = 0.f;
    int e = beg;
#pragma unroll 1
    for (; e + 8 <= end; e += 8) {
        int2 c[8];
#pragma unroll
        for (int j = 0; j < 8; j++) c[j] = cv[e + j];
        float xv[8];
#pragma unroll
        for (int j = 0; j < 8; j++) {
            int col = __builtin_amdgcn_readfirstlane(c[j].x);
            const float* xr = (col < split) ? (x_lo + (size_t)col * EMBED_DIM)
                                            : (x_hi + (size_t)(col - split) * EMBED_DIM);
            xv[j] = xr[lane];
        }
#pragma unroll
        for (int j = 0; j < 8; j++) {
            float v = __int_as_float(__builtin_amdgcn_readfirstlane(c[j].y));
            acc += v * xv[j];
        }
    }
#pragma unroll 1
    for (; e < end; e++) {
        int2 cc = cv[e];
        int col = __builtin_amdgcn_readfirstlane(cc.x);
        float v = __int_as_float(__builtin_amdgcn_readfirstlane(cc.y));
        const float* xr = (col < split) ? (x_lo + (size_t)col * EMBED_DIM)
                                        : (x_hi + (size_t)(col - split) * EMBED_DIM);
        acc += v * xr[lane];
    }
    return acc;
}

__global__ void k_spmm(const int* __restrict__ offs, const int2* __restrict__ cv,
                       const float* __restrict__ x_lo, const float* __restrict__ x_hi,
                       int split, float* __restrict__ out) {
    int row = (blockIdx.x * blockDim.x + threadIdx.x) >> 6;
    int lane = threadIdx.x & 63;
    if (row >= N_NODES) return;
    row = __builtin_amdgcn_readfirstlane(row);
    int beg = __builtin_amdgcn_readfirstlane(offs[row]);
    int end = __builtin_amdgcn_readfirstlane(offs[row + 1]);
    float acc = spmm_row(beg, end, lane, cv, x_lo, x_hi, split);
    out[(size_t)row * EMBED_DIM + lane] = acc;
}

// Last layer: only batch rows are consumed — compute just those.
__global__ void k_spmm_batch(const int* __restrict__ offs, const int2* __restrict__ cv,
                             const float* __restrict__ x,
                             const int* __restrict__ users, const int* __restrict__ items,
                             float* __restrict__ u_acc, float* __restrict__ i_acc,
                             int batch) {
    int w = (blockIdx.x * blockDim.x + threadIdx.x) >> 6;
    int lane = threadIdx.x & 63;
    if (w >= 2 * batch) return;
    int b, row;
    float* dst;
    if (w < batch) { b = w;         row = users[b];             dst = u_acc; }
    else           { b = w - batch; row = NUM_USERS + items[b]; dst = i_acc; }
    row = __builtin_amdgcn_readfirstlane(row);
    int beg = __builtin_amdgcn_readfirstlane(offs[row]);
    int end = __builtin_amdgcn_readfirstlane(offs[row + 1]);
    float acc = spmm_row(beg, end, lane, cv, x, x, 0);
    dst[(size_t)b * EMBED_DIM + lane] += acc;
}

// ---------------------------------------------------------------------------
__global__ void k_gather(const int* __restrict__ users, const int* __restrict__ items,
                         const float* __restrict__ x_lo, const float* __restrict__ x_hi,
                         int split, float* __restrict__ u_acc, float* __restrict__ i_acc,
                         int add, int batch) {
    int wave = (blockIdx.x * blockDim.x + threadIdx.x) >> 6;
    int lane = threadIdx.x & 63;
    if (wave >= batch) return;
    int nu = users[wave];
    int ni = NUM_USERS + items[wave];
    const float* ur = (nu < split) ? (x_lo + (size_t)nu * EMBED_DIM)
                                   : (x_hi + (size_t)(nu - split) * EMBED_DIM);
    const float* ir = (ni < split) ? (x_lo + (size_t)ni * EMBED_DIM)
                                   : (x_hi + (size_t)(ni - split) * EMBED_DIM);
    float uv = ur[lane];
    float iv = ir[lane];
    size_t o = (size_t)wave * EMBED_DIM + lane;
    if (add) { u_acc[o] += uv; i_acc[o] += iv; }
    else     { u_acc[o]  = uv; i_acc[o]  = iv; }
}

__global__ void k_dot(const float* __restrict__ u_acc, const float* __restrict__ i_acc,
                      float* __restrict__ out, int batch) {
    int wave = (blockIdx.x * blockDim.x + threadIdx.x) >> 6;
    int lane = threadIdx.x & 63;
    if (wave >= batch) return;
    size_t o = (size_t)wave * EMBED_DIM + lane;
    float p = u_acc[o] * i_acc[o];
#pragma unroll
    for (int d = 32; d > 0; d >>= 1) p += __shfl_down(p, d, 64);
    if (lane == 0) out[wave] = p * (1.0f / 16.0f);
}

// ---------------------------------------------------------------------------

extern "C" void kernel_launch(void* const* d_in, const int* in_sizes, int n_in,
                              void* d_out, int out_size, void* d_ws, size_t ws_size,
                              hipStream_t stream) {
    const int*   users    = (const int*)  d_in[0];
    const int*   items    = (const int*)  d_in[1];
    const int*   adj_rows = (const int*)  d_in[2];
    const int*   adj_cols = (const int*)  d_in[3];
    const float* adj_vals = (const float*)d_in[4];
    const float* user_emb = (const float*)d_in[5];
    const float* item_emb = (const float*)d_in[6];
    float* out = (float*)d_out;

    const int batch = in_sizes[0];
    const int nnz   = in_sizes[2];

    char* p = (char*)d_ws;
    auto alloc = [&](size_t bytes) -> char* {
        char* r = p;
        p += (bytes + 255) & ~(size_t)255;
        return r;
    };
    int*   offs          = (int*)  alloc(((size_t)N_NODES + 1) * 4);
    int*   bhist         = (int*)  alloc(256 * 4);
    int*   bucket_off    = (int*)  alloc(256 * 4);
    int*   bucket_cursor = (int*)  alloc(256 * 4);
    int2*  cv            = (int2*) alloc((size_t)nnz * 8);            // final CSR (col,val)
    // bufA+bufB region doubles as the int2 staging array (dead before spmm1):
    float* bufA          = (float*)alloc(2 * (size_t)N_NODES * EMBED_DIM * 4);
    float* bufB          = bufA + (size_t)N_NODES * EMBED_DIM;
    int2*  staging       = (int2*)bufA;                               // nnz*8 = 38.4 MB
    float* u_acc         = (float*)alloc((size_t)batch * EMBED_DIM * 4);
    float* i_acc         = (float*)alloc((size_t)batch * EMBED_DIM * 4);

    const int g_bhist  = (nnz + 256 * 32 - 1) / (256 * 32);
    const int g_bin    = (nnz + BIN_CHUNK - 1) / BIN_CHUNK;
    const int g_nodes  = (N_NODES + 3) / 4;          // 4 rows (waves) / 256-thr block
    const int g_batch  = (batch + 3) / 4;
    const int g_batch2 = (2 * batch + 3) / 4;

    // ---- CSR build (bucket-staged counting sort) ----
    hipMemsetAsync(bhist, 0, 256 * 4, stream);
    k_bucket_hist<<<g_bhist, 256, 0, stream>>>(adj_rows, bhist, nnz);
    k_bucket_scan<<<1, 256, 0, stream>>>(bhist, bucket_off, bucket_cursor, offs, nnz);
    k_bin<<<g_bin, 256, 0, stream>>>(adj_rows, adj_cols, adj_vals, bucket_cursor, staging, nnz);
    k_scatter2<<<B_BUCKETS, 1024, 0, stream>>>(staging, bucket_off, offs, cv);

    // ---- layer 0 (ego) contribution ----
    k_gather<<<g_batch, 256, 0, stream>>>(users, items, user_emb, item_emb,
                                          NUM_USERS, u_acc, i_acc, /*add=*/0, batch);

    // ---- layer 1: cur1 = A * ego ----
    k_spmm<<<g_nodes, 256, 0, stream>>>(offs, cv, user_emb, item_emb, NUM_USERS, bufA);
    k_gather<<<g_batch, 256, 0, stream>>>(users, items, bufA, bufA, 0,
                                          u_acc, i_acc, 1, batch);

    // ---- layer 2: cur2 = A * cur1 ----
    k_spmm<<<g_nodes, 256, 0, stream>>>(offs, cv, bufA, bufA, 0, bufB);
    k_gather<<<g_batch, 256, 0, stream>>>(users, items, bufB, bufB, 0,
                                          u_acc, i_acc, 1, batch);

    // ---- layer 3: only batch rows needed — fused spmm+gather ----
    k_spmm_batch<<<g_batch2, 256, 0, stream>>>(offs, cv, bufB, users, items,
                                               u_acc, i_acc, batch);

    // ---- final dot ----
    k_dot<<<g_batch, 256, 0, stream>>>(u_acc, i_acc, out, batch);
}

// Round 5
// 524.283 us; speedup vs baseline: 3.7122x; 1.2251x over previous
//
#include <hip/hip_runtime.h>
#include <hip/hip_bf16.h>

#define NUM_USERS 100000
#define NUM_ITEMS 50000
#define EMBED_DIM 64
#define N_NODES   150000                 // NUM_USERS + NUM_ITEMS
#define ROW_SHIFT 10                     // 1024 rows per bucket
#define ROWS_PER_BUCKET 1024
#define B_BUCKETS ((N_NODES + ROWS_PER_BUCKET - 1) / ROWS_PER_BUCKET)   // 147
#define BIN_CHUNK 2048                   // edges per k_bin block (8/thread)
#define COL_MASK 0x3FFFF                 // 18 bits for col (N_NODES < 262144)

typedef unsigned short ushort_t;

__device__ __forceinline__ float bf16_to_f32(ushort_t u) {
    return __uint_as_float(((unsigned)u) << 16);
}
__device__ __forceinline__ ushort_t f32_to_bf16(float f) {
    return __builtin_bit_cast(ushort_t, __float2bfloat16(f));   // RNE
}

// ---------------------------------------------------------------------------
// Pass 0: coarse bucket histogram (147 counters) via per-block LDS hist.
// ---------------------------------------------------------------------------
__global__ void k_bucket_hist(const int* __restrict__ rows, int* __restrict__ bhist, int nnz) {
    __shared__ int lh[256];
    int t = threadIdx.x;
    lh[t] = 0;
    __syncthreads();
    int base = blockIdx.x * (256 * 32);
#pragma unroll
    for (int k = 0; k < 32; k++) {
        int idx = base + k * 256 + t;
        if (idx < nnz) atomicAdd(&lh[rows[idx] >> ROW_SHIFT], 1);
    }
    __syncthreads();
    if (t < B_BUCKETS && lh[t] > 0) atomicAdd(&bhist[t], lh[t]);
}

// Pass 0b: single-block scan of bucket counts -> bucket_off, cursors, sentinel.
__global__ void k_bucket_scan(const int* __restrict__ bhist, int* __restrict__ bucket_off,
                              int* __restrict__ bucket_cursor, int* __restrict__ offs, int nnz) {
    __shared__ int lds[256];
    int t = threadIdx.x;
    int v = (t < B_BUCKETS) ? bhist[t] : 0;
    lds[t] = v;
    __syncthreads();
    for (int d = 1; d < 256; d <<= 1) {
        int y = (t >= d) ? lds[t - d] : 0;
        __syncthreads();
        lds[t] += y;
        __syncthreads();
    }
    int excl = lds[t] - v;
    if (t < B_BUCKETS) {
        bucket_off[t] = excl;
        bucket_cursor[t] = excl;
    }
    if (t == 0) {
        bucket_off[B_BUCKETS] = nnz;
        offs[N_NODES] = nnz;
    }
}

// ---------------------------------------------------------------------------
// Pass 1: LDS-binned staging, packed int2 {col | lrow<<18, val} + uint8 bucket.
// Flushes per-bucket contiguous runs (full-line writes, bucket-major layout).
// ---------------------------------------------------------------------------
__global__ void __launch_bounds__(256) k_bin(const int* __restrict__ rows,
                                             const int* __restrict__ cols,
                                             const float* __restrict__ vals,
                                             int* __restrict__ bucket_cursor,
                                             int2* __restrict__ staging, int nnz) {
    __shared__ int  ccnt[256];
    __shared__ int  cpos[256];
    __shared__ int  gdst[256];
    __shared__ int2 entries[BIN_CHUNK];            // 16 KB
    __shared__ unsigned char ebuck[BIN_CHUNK];     // 2 KB

    int t = threadIdx.x;
    int base = blockIdx.x * BIN_CHUNK;
    ccnt[t] = 0;
    __syncthreads();

    int myrow[BIN_CHUNK / 256];
#pragma unroll
    for (int k = 0; k < BIN_CHUNK / 256; k++) {
        int idx = base + k * 256 + t;
        int r = (idx < nnz) ? rows[idx] : -1;
        myrow[k] = r;
        if (r >= 0) atomicAdd(&ccnt[r >> ROW_SHIFT], 1);
    }
    __syncthreads();

    int c = ccnt[t];
    cpos[t] = c;
    __syncthreads();
    for (int d = 1; d < 256; d <<= 1) {
        int y = (t >= d) ? cpos[t - d] : 0;
        __syncthreads();
        cpos[t] += y;
        __syncthreads();
    }
    int total = cpos[255];
    int excl = cpos[t] - c;
    __syncthreads();
    cpos[t] = excl;
    __syncthreads();

#pragma unroll
    for (int k = 0; k < BIN_CHUNK / 256; k++) {
        int r = myrow[k];
        if (r >= 0) {
            int idx = base + k * 256 + t;
            int b = r >> ROW_SHIFT;
            int lrow = r & (ROWS_PER_BUCKET - 1);
            int slot = atomicAdd(&cpos[b], 1);
            entries[slot] = make_int2(cols[idx] | (lrow << 18), __float_as_int(vals[idx]));
            ebuck[slot] = (unsigned char)b;
        }
    }
    __syncthreads();

    if (t < B_BUCKETS && ccnt[t] > 0) {
        int g = atomicAdd(&bucket_cursor[t], ccnt[t]);
        gdst[t] = g - (cpos[t] - ccnt[t]);
    }
    __syncthreads();

    for (int i = t; i < total; i += 256) {
        staging[gdst[ebuck[i]] + i] = entries[i];
    }
}

// ---------------------------------------------------------------------------
// Pass 2: one block owns one bucket (1024 rows). Count -> scan -> scatter,
// all writes of each cv cache line come from one block.
// ---------------------------------------------------------------------------
__global__ void __launch_bounds__(1024) k_scatter2(const int2* __restrict__ staging,
                                                   const int* __restrict__ bucket_off,
                                                   int* __restrict__ offs,
                                                   int2* __restrict__ cv) {
    __shared__ int rc[ROWS_PER_BUCKET];
    int b = blockIdx.x;
    int t = threadIdx.x;
    int beg = bucket_off[b], end = bucket_off[b + 1];
    int row0 = b << ROW_SHIFT;

    rc[t] = 0;
    __syncthreads();
    for (int i = beg + t; i < end; i += 1024)
        atomicAdd(&rc[staging[i].x >> 18], 1);
    __syncthreads();

    int c = rc[t];
    for (int d = 1; d < 1024; d <<= 1) {
        int y = (t >= d) ? rc[t - d] : 0;
        __syncthreads();
        rc[t] += y;
        __syncthreads();
    }
    int excl = rc[t] - c;
    int row = row0 + t;
    if (row < N_NODES) offs[row] = beg + excl;
    __syncthreads();
    rc[t] = excl;
    __syncthreads();

    for (int i = beg + t; i < end; i += 1024) {
        int2 e = staging[i];
        int pos = beg + atomicAdd(&rc[e.x >> 18], 1);
        cv[pos] = make_int2(e.x & COL_MASK, e.y);
    }
}

// ---------------------------------------------------------------------------
// Convert the fp32 ego table (user_emb ++ item_emb) to one bf16 table.
// ---------------------------------------------------------------------------
__global__ void k_convert(const float* __restrict__ ue, const float* __restrict__ ie,
                          ushort_t* __restrict__ xb) {
    int i = blockIdx.x * blockDim.x + threadIdx.x;   // float4 index
    const int n4 = (N_NODES * EMBED_DIM) / 4;
    if (i >= n4) return;
    const int usplit = (NUM_USERS * EMBED_DIM) / 4;
    float4 f = (i < usplit) ? ((const float4*)ue)[i] : ((const float4*)ie)[i - usplit];
    ushort4 o;
    o.x = f32_to_bf16(f.x);
    o.y = f32_to_bf16(f.y);
    o.z = f32_to_bf16(f.z);
    o.w = f32_to_bf16(f.w);
    ((ushort4*)xb)[i] = o;
}

// ---------------------------------------------------------------------------
// SpMM row body (bf16 x): one wave per row, lane = dim. Edge stream is
// wave-uniform (scalarized via readfirstlane -> s_load). 2-deep software
// pipeline: up to 16 gathers in flight per wave. Row = 128 B = 1 cache line.
// ---------------------------------------------------------------------------
__device__ __forceinline__ float spmm_row(int beg, int end, int lane,
                                          const int2* __restrict__ cv,
                                          const ushort_t* __restrict__ xb) {
    float acc = 0.f;
    int e = beg;
    int n8 = (end - beg) >> 3;
    float    v0[8], v1[8];
    ushort_t r0[8], r1[8];

    if (n8 > 0) {
#pragma unroll
        for (int j = 0; j < 8; j++) {                       // prologue: group 0
            int2 c = cv[e + j];
            int col = __builtin_amdgcn_readfirstlane(c.x);
            v0[j] = __int_as_float(__builtin_amdgcn_readfirstlane(c.y));
            r0[j] = xb[(size_t)col * EMBED_DIM + lane];
        }
        e += 8;
#pragma unroll 1
        for (int g = 1; g < n8; g++) {
#pragma unroll
            for (int j = 0; j < 8; j++) {                   // issue next group
                int2 c = cv[e + j];
                int col = __builtin_amdgcn_readfirstlane(c.x);
                v1[j] = __int_as_float(__builtin_amdgcn_readfirstlane(c.y));
                r1[j] = xb[(size_t)col * EMBED_DIM + lane];
            }
            e += 8;
#pragma unroll
            for (int j = 0; j < 8; j++)                     // consume current
                acc += v0[j] * bf16_to_f32(r0[j]);
#pragma unroll
            for (int j = 0; j < 8; j++) { v0[j] = v1[j]; r0[j] = r1[j]; }
        }
#pragma unroll
        for (int j = 0; j < 8; j++)                         // epilogue
            acc += v0[j] * bf16_to_f32(r0[j]);
    }
#pragma unroll 1
    for (; e < end; e++) {                                  // remainder
        int2 c = cv[e];
        int col = __builtin_amdgcn_readfirstlane(c.x);
        float v = __int_as_float(__builtin_amdgcn_readfirstlane(c.y));
        acc += v * bf16_to_f32(xb[(size_t)col * EMBED_DIM + lane]);
    }
    return acc;
}

__global__ void k_spmm(const int* __restrict__ offs, const int2* __restrict__ cv,
                       const ushort_t* __restrict__ xb, ushort_t* __restrict__ out) {
    int row = (blockIdx.x * blockDim.x + threadIdx.x) >> 6;
    int lane = threadIdx.x & 63;
    if (row >= N_NODES) return;
    row = __builtin_amdgcn_readfirstlane(row);
    int beg = __builtin_amdgcn_readfirstlane(offs[row]);
    int end = __builtin_amdgcn_readfirstlane(offs[row + 1]);
    float acc = spmm_row(beg, end, lane, cv, xb);
    out[(size_t)row * EMBED_DIM + lane] = f32_to_bf16(acc);
}

// Last layer: only batch rows are consumed — compute just those, accumulate fp32.
__global__ void k_spmm_batch(const int* __restrict__ offs, const int2* __restrict__ cv,
                             const ushort_t* __restrict__ xb,
                             const int* __restrict__ users, const int* __restrict__ items,
                             float* __restrict__ u_acc, float* __restrict__ i_acc,
                             int batch) {
    int w = (blockIdx.x * blockDim.x + threadIdx.x) >> 6;
    int lane = threadIdx.x & 63;
    if (w >= 2 * batch) return;
    int b, row;
    float* dst;
    if (w < batch) { b = w;         row = users[b];             dst = u_acc; }
    else           { b = w - batch; row = NUM_USERS + items[b]; dst = i_acc; }
    row = __builtin_amdgcn_readfirstlane(row);
    int beg = __builtin_amdgcn_readfirstlane(offs[row]);
    int end = __builtin_amdgcn_readfirstlane(offs[row + 1]);
    float acc = spmm_row(beg, end, lane, cv, xb);
    dst[(size_t)b * EMBED_DIM + lane] += acc;
}

// ---------------------------------------------------------------------------
// Layer-0 (exact fp32) init of batch accumulators from the original tables.
// ---------------------------------------------------------------------------
__global__ void k_gather_f32(const int* __restrict__ users, const int* __restrict__ items,
                             const float* __restrict__ ue, const float* __restrict__ ie,
                             float* __restrict__ u_acc, float* __restrict__ i_acc, int batch) {
    int w = (blockIdx.x * blockDim.x + threadIdx.x) >> 6;
    int lane = threadIdx.x & 63;
    if (w >= batch) return;
    int nu = users[w];
    int ni = items[w];
    size_t o = (size_t)w * EMBED_DIM + lane;
    u_acc[o] = ue[(size_t)nu * EMBED_DIM + lane];
    i_acc[o] = ie[(size_t)ni * EMBED_DIM + lane];
}

// Layers 1,2: accumulate bf16 layer rows into fp32 accumulators.
__global__ void k_gather_bf16(const int* __restrict__ users, const int* __restrict__ items,
                              const ushort_t* __restrict__ xb,
                              float* __restrict__ u_acc, float* __restrict__ i_acc, int batch) {
    int w = (blockIdx.x * blockDim.x + threadIdx.x) >> 6;
    int lane = threadIdx.x & 63;
    if (w >= batch) return;
    int nu = users[w];
    int ni = NUM_USERS + items[w];
    size_t o = (size_t)w * EMBED_DIM + lane;
    u_acc[o] += bf16_to_f32(xb[(size_t)nu * EMBED_DIM + lane]);
    i_acc[o] += bf16_to_f32(xb[(size_t)ni * EMBED_DIM + lane]);
}

__global__ void k_dot(const float* __restrict__ u_acc, const float* __restrict__ i_acc,
                      float* __restrict__ out, int batch) {
    int w = (blockIdx.x * blockDim.x + threadIdx.x) >> 6;
    int lane = threadIdx.x & 63;
    if (w >= batch) return;
    size_t o = (size_t)w * EMBED_DIM + lane;
    float p = u_acc[o] * i_acc[o];
#pragma unroll
    for (int d = 32; d > 0; d >>= 1) p += __shfl_down(p, d, 64);
    if (lane == 0) out[w] = p * (1.0f / 16.0f);
}

// ---------------------------------------------------------------------------

extern "C" void kernel_launch(void* const* d_in, const int* in_sizes, int n_in,
                              void* d_out, int out_size, void* d_ws, size_t ws_size,
                              hipStream_t stream) {
    const int*   users    = (const int*)  d_in[0];
    const int*   items    = (const int*)  d_in[1];
    const int*   adj_rows = (const int*)  d_in[2];
    const int*   adj_cols = (const int*)  d_in[3];
    const float* adj_vals = (const float*)d_in[4];
    const float* user_emb = (const float*)d_in[5];
    const float* item_emb = (const float*)d_in[6];
    float* out = (float*)d_out;

    const int batch = in_sizes[0];
    const int nnz   = in_sizes[2];

    char* p = (char*)d_ws;
    auto alloc = [&](size_t bytes) -> char* {
        char* r = p;
        p += (bytes + 255) & ~(size_t)255;
        return r;
    };
    const size_t xb_bytes = (size_t)N_NODES * EMBED_DIM * 2;       // 19.2 MB
    int*      offs          = (int*)  alloc(((size_t)N_NODES + 1) * 4);
    int*      bhist         = (int*)  alloc(256 * 4);
    int*      bucket_off    = (int*)  alloc(256 * 4);
    int*      bucket_cursor = (int*)  alloc(256 * 4);
    int2*     cv            = (int2*) alloc((size_t)nnz * 8);      // final CSR (col,val)
    // region overlays: int2 staging (build phase) vs xbA+xbB (layer buffers)
    size_t    region_bytes  = (size_t)nnz * 8;
    if (region_bytes < 2 * xb_bytes) region_bytes = 2 * xb_bytes;
    char*     region        = alloc(region_bytes);
    int2*     staging       = (int2*)region;
    ushort_t* xbA           = (ushort_t*)region;
    ushort_t* xbB           = (ushort_t*)(region + xb_bytes);
    ushort_t* xb_ego        = (ushort_t*)alloc(xb_bytes);
    float*    u_acc         = (float*)alloc((size_t)batch * EMBED_DIM * 4);
    float*    i_acc         = (float*)alloc((size_t)batch * EMBED_DIM * 4);

    const int g_bhist  = (nnz + 256 * 32 - 1) / (256 * 32);
    const int g_bin    = (nnz + BIN_CHUNK - 1) / BIN_CHUNK;
    const int g_conv   = ((N_NODES * EMBED_DIM / 4) + 255) / 256;
    const int g_nodes  = (N_NODES + 3) / 4;          // 4 rows (waves) / 256-thr block
    const int g_batch  = (batch + 3) / 4;
    const int g_batch2 = (2 * batch + 3) / 4;

    // ---- CSR build (bucket-staged counting sort) ----
    hipMemsetAsync(bhist, 0, 256 * 4, stream);
    k_bucket_hist<<<g_bhist, 256, 0, stream>>>(adj_rows, bhist, nnz);
    k_bucket_scan<<<1, 256, 0, stream>>>(bhist, bucket_off, bucket_cursor, offs, nnz);
    k_bin<<<g_bin, 256, 0, stream>>>(adj_rows, adj_cols, adj_vals, bucket_cursor, staging, nnz);
    k_scatter2<<<B_BUCKETS, 1024, 0, stream>>>(staging, bucket_off, offs, cv);

    // ---- bf16 ego table ----
    k_convert<<<g_conv, 256, 0, stream>>>(user_emb, item_emb, xb_ego);

    // ---- layer 0 (ego, exact fp32) ----
    k_gather_f32<<<g_batch, 256, 0, stream>>>(users, items, user_emb, item_emb,
                                              u_acc, i_acc, batch);

    // ---- layer 1: xbA = A * ego ----
    k_spmm<<<g_nodes, 256, 0, stream>>>(offs, cv, xb_ego, xbA);
    k_gather_bf16<<<g_batch, 256, 0, stream>>>(users, items, xbA, u_acc, i_acc, batch);

    // ---- layer 2: xbB = A * xbA ----
    k_spmm<<<g_nodes, 256, 0, stream>>>(offs, cv, xbA, xbB);
    k_gather_bf16<<<g_batch, 256, 0, stream>>>(users, items, xbB, u_acc, i_acc, batch);

    // ---- layer 3: only batch rows needed — fused spmm+gather (fp32 acc) ----
    k_spmm_batch<<<g_batch2, 256, 0, stream>>>(offs, cv, xbB, users, items,
                                               u_acc, i_acc, batch);

    // ---- final dot ----
    k_dot<<<g_batch, 256, 0, stream>>>(u_acc, i_acc, out, batch);
}